// Round 9
// baseline (3156.401 us; speedup 1.0000x reference)
//
#include <hip/hip_runtime.h>
#include <math.h>

#define DD 768
#define HH 384
#define LL 32
#define BSZ 4096
#define CAP 256          // max batches handled by fast gathered fp64 repair
#define EPS_DEC 4e-7     // decision margin (fp16x2-MFMA path gs error ~1e-8)

typedef _Float16 half8 __attribute__((ext_vector_type(8)));
typedef _Float16 half4 __attribute__((ext_vector_type(4)));
typedef float floatx4 __attribute__((ext_vector_type(4)));

static __device__ __forceinline__ float geluf(float x) {
    return 0.5f * x * (1.0f + erff(x * 0.70710678118654752440f));
}
static __device__ __forceinline__ double gelud(double x) {
    return 0.5 * x * (1.0 + erf(x * 0.70710678118654752440));
}

// ---------------------------------------------------------------------------
// Serial fp64 tail. lgd[32] -> gsd[32], st/en; flag if any decision margin
// < eps (eps=0 disables flagging for the repair path).
// ---------------------------------------------------------------------------
static __device__ void tail_fp64(const double* lgd, double sigma, double* gsd,
                                 int* pst, int* pen, int* pflag, double eps) {
    double kern[5];
    {
        double inv = 1.0 / sigma, ssum = 0.;
#pragma unroll
        for (int j = 0; j < 5; j++) {
            double t = (double)(j - 2) * inv;
            kern[j] = exp(-0.5 * t * t);
            ssum += kern[j];
        }
#pragma unroll
        for (int j = 0; j < 5; j++) kern[j] /= ssum;
    }
    double kp[32];
    {
        double mx = lgd[0];
        for (int i = 1; i < 32; i++) mx = fmax(mx, lgd[i]);
        double sum = 0.;
        for (int i = 0; i < 32; i++) { kp[i] = exp(lgd[i] - mx); sum += kp[i]; }
        for (int i = 0; i < 32; i++) kp[i] /= sum;
    }
    double sm[32];
    for (int i = 0; i < 32; i++) {
        double a = 0.;
#pragma unroll
        for (int j = 0; j < 5; j++) {
            int t = i + j - 2;
            if (t >= 0 && t < 32) a += kern[j] * kp[t];
        }
        sm[i] = a;
    }
    {
        double mx = sm[0];
        for (int i = 1; i < 32; i++) mx = fmax(mx, sm[i]);
        double sum = 0.;
        for (int i = 0; i < 32; i++) { gsd[i] = exp(sm[i] - mx); sum += gsd[i]; }
        for (int i = 0; i < 32; i++) gsd[i] /= sum;
    }
    int am = 0;
    double bv = gsd[0];
    for (int i = 1; i < 32; i++)
        if (gsd[i] > bv) { bv = gsd[i]; am = i; }
    int flag = 0;
    if (eps > 0.) {
        double second = -INFINITY;
        for (int i = 0; i < 32; i++)
            if (i != am && gsd[i] > second) second = gsd[i];
        if (bv - second < eps) flag = 1;
    }
    double cs[33];
    cs[0] = 0.;
    double c = 0.;
    for (int i = 0; i < 32; i++) { c += gsd[i]; cs[i + 1] = c; }
    double best = -INFINITY;
    int bs0 = 0, be0 = 0;
    const int wsz[3] = {1, 3, 5};
    for (int wi = 0; wi < 3; wi++) {
        int w = wsz[wi];
        for (int st = 0; st <= 32 - w; st++) {
            if (am >= st && am < st + w) {
                double sc = cs[st + w] - cs[st];
                if (sc > best) { best = sc; bs0 = st; be0 = st + w; }
            }
        }
    }
    if (eps > 0.) {
        int near = 0;
        for (int wi = 0; wi < 3; wi++) {
            int w = wsz[wi];
            for (int st = 0; st <= 32 - w; st++) {
                if (am >= st && am < st + w) {
                    double sc = cs[st + w] - cs[st];
                    if (sc > best - eps) near++;
                }
            }
        }
        if (near >= 2) flag = 1;
    }
    *pst = bs0;
    *pen = be0;
    *pflag = flag;
}

static __device__ __forceinline__ void write_outputs(float* out, int b,
                                                     const double* gsd,
                                                     const double* lgd,
                                                     int st0, int en0, int l) {
    float* o_gs = out;
    float* o_idx = out + 131072;
    float* o_st = out + 139264;
    float* o_et = out + 143360;
    float* o_mask = out + 147456;
    float* o_ok = out + 278528;
    if (l < 32) {
        o_gs[(b << 5) + l] = (float)gsd[l];
        o_mask[(b << 5) + l] = (l >= st0 && l <= en0) ? 1.f : 0.f;
        o_ok[(b << 5) + l] = (float)lgd[l];
    }
    if (l == 0) {
        o_idx[(b << 1)] = (float)st0;
        o_idx[(b << 1) + 1] = (float)en0;
        o_st[b] = (float)((double)st0 / 31.0);
        o_et[b] = (float)((double)en0 / 31.0);
    }
}

// ---------------------------------------------------------------------------
// Per-row mean / rstd over 768 floats (double accum). One wave per row.
// ---------------------------------------------------------------------------
__global__ __launch_bounds__(256) void row_stats_k(const float* __restrict__ X,
                                                   float* __restrict__ mean,
                                                   float* __restrict__ rstd,
                                                   int nrows) {
    int w = (int)((blockIdx.x * blockDim.x + threadIdx.x) >> 6);
    int lane = threadIdx.x & 63;
    if (w >= nrows) return;
    const float* row = X + (size_t)w * DD;
    double s = 0., q = 0.;
#pragma unroll
    for (int i = 0; i < 3; i++) {
        float4 v = *(const float4*)(row + ((lane + (i << 6)) << 2));
        double a = v.x, b = v.y, c = v.z, d = v.w;
        s += a + b + c + d;
        q += a * a + b * b + c * c + d * d;
    }
#pragma unroll
    for (int m = 1; m < 64; m <<= 1) {
        s += __shfl_xor(s, m, 64);
        q += __shfl_xor(q, m, 64);
    }
    if (lane == 0) {
        double mu = s * (1.0 / 768.0);
        double var = q * (1.0 / 768.0) - mu * mu;
        mean[w] = (float)mu;
        rstd[w] = (float)rsqrt(var + 1e-5);
    }
}

// ---------------------------------------------------------------------------
// Split fp32 W[k][n] (768 x N) into fp16 hi/lo, TRANSPOSED to [n][768].
// a = hi + lo*2^-12 with lo = fp16((a-hi)*4096) kept in normal range.
// Grid: (N/64, 768/64).
// ---------------------------------------------------------------------------
__global__ __launch_bounds__(256) void wsplit_k(const float* __restrict__ W,
                                                unsigned short* __restrict__ hiT,
                                                unsigned short* __restrict__ loT,
                                                int N) {
    __shared__ float t[64][65];
    const int tid = threadIdx.x;
    const int n0 = blockIdx.x << 6, k0 = blockIdx.y << 6;
    const int kr = tid >> 4, nc = (tid & 15) << 2;
#pragma unroll
    for (int i = 0; i < 4; i++) {
        float4 v = *(const float4*)&W[(size_t)(k0 + kr + (i << 4)) * N + n0 + nc];
        t[kr + (i << 4)][nc] = v.x;
        t[kr + (i << 4)][nc + 1] = v.y;
        t[kr + (i << 4)][nc + 2] = v.z;
        t[kr + (i << 4)][nc + 3] = v.w;
    }
    __syncthreads();
    const int nr = tid >> 2, kc = (tid & 3) << 4;
    half8 hv0 = {}, hv1 = {}, lv0 = {}, lv1 = {};
#pragma unroll
    for (int j = 0; j < 8; j++) {
        float x = t[kc + j][nr];
        _Float16 h = (_Float16)x;
        hv0[j] = h;
        lv0[j] = (_Float16)((x - (float)h) * 4096.f);
    }
#pragma unroll
    for (int j = 0; j < 8; j++) {
        float x = t[kc + 8 + j][nr];
        _Float16 h = (_Float16)x;
        hv1[j] = h;
        lv1[j] = (_Float16)((x - (float)h) * 4096.f);
    }
    size_t base = (size_t)(n0 + nr) * DD + k0 + kc;
    *(half8*)&hiT[base] = hv0;
    *(half8*)&hiT[base + 8] = hv1;
    *(half8*)&loT[base] = lv0;
    *(half8*)&loT[base + 8] = lv1;
}

// ---------------------------------------------------------------------------
// Out = gelu( LN(A) @ W + bias ) via fp16x2 split-precision MFMA.
// 128x128 tile, 4 waves (2x2), 64x64/wave, BK=32, mfma_f32_16x16x32_f16.
// Double-buffered LDS, ONE barrier per k-tile: global loads for tile t+1
// issue before the MFMA block (latency hides under ~48 MFMAs); LN+split
// writes to the other buffer after. MFMA order unchanged (bit-identical).
// ---------------------------------------------------------------------------
__global__ __launch_bounds__(256) void gemm_ln_gelu_k(
    const float* __restrict__ A, const float* __restrict__ mean,
    const float* __restrict__ rstd, const float* __restrict__ lng,
    const float* __restrict__ lnb, const unsigned short* __restrict__ WhiT,
    const unsigned short* __restrict__ WloT, const float* __restrict__ bias,
    float* __restrict__ Out) {
    __shared__ _Float16 Ah[2][4][128][8];
    __shared__ _Float16 Al[2][4][128][8];
    __shared__ _Float16 Bh[2][4][128][8];
    __shared__ _Float16 Bl[2][4][128][8];
    const int tid = threadIdx.x;
    const int m0 = blockIdx.x << 7;
    const int n0 = blockIdx.y << 7;
    const int l = tid & 63;
    const int wv = tid >> 6;
    const int wm = (wv >> 1) << 6;      // wave row base 0/64
    const int wn = (wv & 1) << 6;       // wave col base 0/64
    const int lm = l & 15, lg = l >> 4;
    const int ar = tid >> 3;            // rows ar, ar+32, ar+64, ar+96
    const int k4 = (tid & 7) << 2;      // k offset 0..28
    const int akg = k4 >> 3, aj = k4 & 7;
    const int br = tid >> 1;            // n-row 0..127
    const int bh16 = (tid & 1) << 4;    // k offset 0/16
    const int bkg = bh16 >> 3;          // 0 or 2

    float mu[4], rs[4];
#pragma unroll
    for (int i = 0; i < 4; i++) {
        mu[i] = mean[m0 + ar + (i << 5)];
        rs[i] = rstd[m0 + ar + (i << 5)];
    }
    floatx4 acc1[4][4] = {};
    floatx4 acc2[4][4] = {};
    const float* Ab = A + (size_t)m0 * DD;
    const unsigned short* WhB = WhiT + (size_t)n0 * DD;
    const unsigned short* WlB = WloT + (size_t)n0 * DD;

    float4 av[4], g4, b4;
    half8 wr0, wr1, ur0, ur1;

    // ---- prologue: load tile 0 + stage into buf 0 ----
    {
        g4 = *(const float4*)&lng[k4];
        b4 = *(const float4*)&lnb[k4];
#pragma unroll
        for (int i = 0; i < 4; i++)
            av[i] = *(const float4*)&Ab[(size_t)(ar + (i << 5)) * DD + k4];
        const unsigned short* sh = WhB + (size_t)br * DD + bh16;
        const unsigned short* sl = WlB + (size_t)br * DD + bh16;
        wr0 = *(const half8*)sh;
        wr1 = *(const half8*)(sh + 8);
        ur0 = *(const half8*)sl;
        ur1 = *(const half8*)(sl + 8);
#pragma unroll
        for (int i = 0; i < 4; i++) {
            int m = ar + (i << 5);
            float x0 = (av[i].x - mu[i]) * rs[i] * g4.x + b4.x;
            float x1 = (av[i].y - mu[i]) * rs[i] * g4.y + b4.y;
            float x2 = (av[i].z - mu[i]) * rs[i] * g4.z + b4.z;
            float x3 = (av[i].w - mu[i]) * rs[i] * g4.w + b4.w;
            _Float16 h0 = (_Float16)x0, h1 = (_Float16)x1;
            _Float16 h2 = (_Float16)x2, h3 = (_Float16)x3;
            half4 hv = {h0, h1, h2, h3};
            half4 lv = {(_Float16)((x0 - (float)h0) * 4096.f),
                        (_Float16)((x1 - (float)h1) * 4096.f),
                        (_Float16)((x2 - (float)h2) * 4096.f),
                        (_Float16)((x3 - (float)h3) * 4096.f)};
            *(half4*)&Ah[0][akg][m][aj] = hv;
            *(half4*)&Al[0][akg][m][aj] = lv;
        }
        *(half8*)&Bh[0][bkg][br][0] = wr0;
        *(half8*)&Bh[0][bkg + 1][br][0] = wr1;
        *(half8*)&Bl[0][bkg][br][0] = ur0;
        *(half8*)&Bl[0][bkg + 1][br][0] = ur1;
    }

    const int NT = DD / 32;   // 24
    for (int t = 0; t < NT; t++) {
        __syncthreads();
        const int cb = t & 1;
        // ---- issue global loads for tile t+1 (latency hides under MFMA) ----
        if (t + 1 < NT) {
            const int kb = (t + 1) << 5;
            g4 = *(const float4*)&lng[kb + k4];
            b4 = *(const float4*)&lnb[kb + k4];
#pragma unroll
            for (int i = 0; i < 4; i++)
                av[i] = *(const float4*)&Ab[(size_t)(ar + (i << 5)) * DD + kb + k4];
            const unsigned short* sh = WhB + (size_t)br * DD + kb + bh16;
            const unsigned short* sl = WlB + (size_t)br * DD + kb + bh16;
            wr0 = *(const half8*)sh;
            wr1 = *(const half8*)(sh + 8);
            ur0 = *(const half8*)sl;
            ur1 = *(const half8*)(sl + 8);
        }
        // ---- MFMA from buf cb ----
        {
            half8 ah[4], al[4];
#pragma unroll
            for (int mi = 0; mi < 4; mi++) {
                ah[mi] = *(const half8*)&Ah[cb][lg][wm + mi * 16 + lm][0];
                al[mi] = *(const half8*)&Al[cb][lg][wm + mi * 16 + lm][0];
            }
#pragma unroll
            for (int ni = 0; ni < 4; ni++) {
                half8 bhv = *(const half8*)&Bh[cb][lg][wn + ni * 16 + lm][0];
                half8 blv = *(const half8*)&Bl[cb][lg][wn + ni * 16 + lm][0];
#pragma unroll
                for (int mi = 0; mi < 4; mi++) {
                    acc1[mi][ni] = __builtin_amdgcn_mfma_f32_16x16x32_f16(
                        ah[mi], bhv, acc1[mi][ni], 0, 0, 0);
                    acc2[mi][ni] = __builtin_amdgcn_mfma_f32_16x16x32_f16(
                        ah[mi], blv, acc2[mi][ni], 0, 0, 0);
                    acc2[mi][ni] = __builtin_amdgcn_mfma_f32_16x16x32_f16(
                        al[mi], bhv, acc2[mi][ni], 0, 0, 0);
                }
            }
        }
        // ---- LN+split + store tile t+1 into the other buffer ----
        if (t + 1 < NT) {
            const int nb = cb ^ 1;
#pragma unroll
            for (int i = 0; i < 4; i++) {
                int m = ar + (i << 5);
                float x0 = (av[i].x - mu[i]) * rs[i] * g4.x + b4.x;
                float x1 = (av[i].y - mu[i]) * rs[i] * g4.y + b4.y;
                float x2 = (av[i].z - mu[i]) * rs[i] * g4.z + b4.z;
                float x3 = (av[i].w - mu[i]) * rs[i] * g4.w + b4.w;
                _Float16 h0 = (_Float16)x0, h1 = (_Float16)x1;
                _Float16 h2 = (_Float16)x2, h3 = (_Float16)x3;
                half4 hv = {h0, h1, h2, h3};
                half4 lv = {(_Float16)((x0 - (float)h0) * 4096.f),
                            (_Float16)((x1 - (float)h1) * 4096.f),
                            (_Float16)((x2 - (float)h2) * 4096.f),
                            (_Float16)((x3 - (float)h3) * 4096.f)};
                *(half4*)&Ah[nb][akg][m][aj] = hv;
                *(half4*)&Al[nb][akg][m][aj] = lv;
            }
            *(half8*)&Bh[nb][bkg][br][0] = wr0;
            *(half8*)&Bh[nb][bkg + 1][br][0] = wr1;
            *(half8*)&Bl[nb][bkg][br][0] = ur0;
            *(half8*)&Bl[nb][bkg + 1][br][0] = ur1;
        }
    }

    // epilogue: combine, bias, gelu, store
    const float S = 0.000244140625f;  // 2^-12
#pragma unroll
    for (int ni = 0; ni < 4; ni++) {
        float bz = bias[n0 + wn + ni * 16 + lm];
#pragma unroll
        for (int mi = 0; mi < 4; mi++) {
#pragma unroll
            for (int r = 0; r < 4; r++) {
                float val = acc1[mi][ni][r] + acc2[mi][ni][r] * S + bz;
                int row = m0 + wm + mi * 16 + (lg << 2) + r;
                Out[(size_t)row * DD + n0 + wn + ni * 16 + lm] = geluf(val);
            }
        }
    }
}

// ---------------------------------------------------------------------------
// gate = tanh(v2 . qa2[batch]); fold LN(v2*gate) into s1,s2 (double accum).
// ---------------------------------------------------------------------------
__global__ __launch_bounds__(256) void gate_stats_k(
    const float* __restrict__ V2, const float* __restrict__ qa2,
    float* __restrict__ s1, float* __restrict__ s2,
    float* __restrict__ logits, const float* __restrict__ b2,
    int rowbase, int nrows) {
    int r = (int)((blockIdx.x * blockDim.x + threadIdx.x) >> 6);
    int lane = threadIdx.x & 63;
    if (r >= nrows) return;
    const float* vr = V2 + (size_t)r * DD;
    const float* qr = qa2 + (size_t)((rowbase + r) >> 5) * DD;
    double dot = 0., s = 0., q = 0.;
#pragma unroll
    for (int i = 0; i < 3; i++) {
        int idx = (lane + (i << 6)) << 2;
        float4 a = *(const float4*)(vr + idx);
        float4 b = *(const float4*)(qr + idx);
        double ax = a.x, ay = a.y, az = a.z, aw = a.w;
        dot += ax * b.x + ay * b.y + az * b.z + aw * b.w;
        s += ax + ay + az + aw;
        q += ax * ax + ay * ay + az * az + aw * aw;
    }
#pragma unroll
    for (int m = 1; m < 64; m <<= 1) {
        dot += __shfl_xor(dot, m, 64);
        s += __shfl_xor(s, m, 64);
        q += __shfl_xor(q, m, 64);
    }
    double gate = tanh(dot);
    double mu = gate * (s * (1.0 / 768.0));
    double var = gate * gate * (q * (1.0 / 768.0)) - mu * mu;
    double rs = rsqrt(var + 1e-5);
    if (lane == 0) {
        s1[r] = (float)(gate * rs);
        s2[r] = (float)(mu * rs);
        logits[rowbase + r] = b2[0];
    }
}

// ---------------------------------------------------------------------------
// logits += gelu( foldedLN(v2) @ W1 + b1 ) @ w2 via fp16x2 MFMA.
// Same double-buffered single-barrier schedule as gemm_ln_gelu_k.
// ---------------------------------------------------------------------------
__global__ __launch_bounds__(256) void gemm_h_logits_k(
    const float* __restrict__ V2, const float* __restrict__ s1,
    const float* __restrict__ s2, const float* __restrict__ gg,
    const float* __restrict__ gb, const unsigned short* __restrict__ WhiT,
    const unsigned short* __restrict__ WloT, const float* __restrict__ b1,
    const float* __restrict__ w2, float* __restrict__ logits) {
    __shared__ _Float16 Ah[2][4][128][8];
    __shared__ _Float16 Al[2][4][128][8];
    __shared__ _Float16 Bh[2][4][128][8];
    __shared__ _Float16 Bl[2][4][128][8];
    __shared__ float red[128][2];
    const int tid = threadIdx.x;
    const int m0 = blockIdx.x << 7;
    const int n0 = blockIdx.y << 7;
    const int l = tid & 63;
    const int wv = tid >> 6;
    const int wm = (wv >> 1) << 6;
    const int wn = (wv & 1) << 6;
    const int lm = l & 15, lg = l >> 4;
    const int ar = tid >> 3;
    const int k4 = (tid & 7) << 2;
    const int akg = k4 >> 3, aj = k4 & 7;
    const int br = tid >> 1;
    const int bh16 = (tid & 1) << 4;
    const int bkg = bh16 >> 3;

    float ss1[4], ss2[4];
#pragma unroll
    for (int i = 0; i < 4; i++) {
        ss1[i] = s1[m0 + ar + (i << 5)];
        ss2[i] = s2[m0 + ar + (i << 5)];
    }
    floatx4 acc1[4][4] = {};
    floatx4 acc2[4][4] = {};
    const float* Ab = V2 + (size_t)m0 * DD;
    const unsigned short* WhB = WhiT + (size_t)n0 * DD;
    const unsigned short* WlB = WloT + (size_t)n0 * DD;

    float4 av[4], g4, b4;
    half8 wr0, wr1, ur0, ur1;

    // ---- prologue: load tile 0 + stage into buf 0 ----
    {
        g4 = *(const float4*)&gg[k4];
        b4 = *(const float4*)&gb[k4];
#pragma unroll
        for (int i = 0; i < 4; i++)
            av[i] = *(const float4*)&Ab[(size_t)(ar + (i << 5)) * DD + k4];
        const unsigned short* sh = WhB + (size_t)br * DD + bh16;
        const unsigned short* sl = WlB + (size_t)br * DD + bh16;
        wr0 = *(const half8*)sh;
        wr1 = *(const half8*)(sh + 8);
        ur0 = *(const half8*)sl;
        ur1 = *(const half8*)(sl + 8);
#pragma unroll
        for (int i = 0; i < 4; i++) {
            int m = ar + (i << 5);
            float x0 = g4.x * (av[i].x * ss1[i] - ss2[i]) + b4.x;
            float x1 = g4.y * (av[i].y * ss1[i] - ss2[i]) + b4.y;
            float x2 = g4.z * (av[i].z * ss1[i] - ss2[i]) + b4.z;
            float x3 = g4.w * (av[i].w * ss1[i] - ss2[i]) + b4.w;
            _Float16 h0 = (_Float16)x0, h1 = (_Float16)x1;
            _Float16 h2 = (_Float16)x2, h3 = (_Float16)x3;
            half4 hv = {h0, h1, h2, h3};
            half4 lv = {(_Float16)((x0 - (float)h0) * 4096.f),
                        (_Float16)((x1 - (float)h1) * 4096.f),
                        (_Float16)((x2 - (float)h2) * 4096.f),
                        (_Float16)((x3 - (float)h3) * 4096.f)};
            *(half4*)&Ah[0][akg][m][aj] = hv;
            *(half4*)&Al[0][akg][m][aj] = lv;
        }
        *(half8*)&Bh[0][bkg][br][0] = wr0;
        *(half8*)&Bh[0][bkg + 1][br][0] = wr1;
        *(half8*)&Bl[0][bkg][br][0] = ur0;
        *(half8*)&Bl[0][bkg + 1][br][0] = ur1;
    }

    const int NT = DD / 32;
    for (int t = 0; t < NT; t++) {
        __syncthreads();
        const int cb = t & 1;
        if (t + 1 < NT) {
            const int kb = (t + 1) << 5;
            g4 = *(const float4*)&gg[kb + k4];
            b4 = *(const float4*)&gb[kb + k4];
#pragma unroll
            for (int i = 0; i < 4; i++)
                av[i] = *(const float4*)&Ab[(size_t)(ar + (i << 5)) * DD + kb + k4];
            const unsigned short* sh = WhB + (size_t)br * DD + kb + bh16;
            const unsigned short* sl = WlB + (size_t)br * DD + kb + bh16;
            wr0 = *(const half8*)sh;
            wr1 = *(const half8*)(sh + 8);
            ur0 = *(const half8*)sl;
            ur1 = *(const half8*)(sl + 8);
        }
        {
            half8 ah[4], al[4];
#pragma unroll
            for (int mi = 0; mi < 4; mi++) {
                ah[mi] = *(const half8*)&Ah[cb][lg][wm + mi * 16 + lm][0];
                al[mi] = *(const half8*)&Al[cb][lg][wm + mi * 16 + lm][0];
            }
#pragma unroll
            for (int ni = 0; ni < 4; ni++) {
                half8 bhv = *(const half8*)&Bh[cb][lg][wn + ni * 16 + lm][0];
                half8 blv = *(const half8*)&Bl[cb][lg][wn + ni * 16 + lm][0];
#pragma unroll
                for (int mi = 0; mi < 4; mi++) {
                    acc1[mi][ni] = __builtin_amdgcn_mfma_f32_16x16x32_f16(
                        ah[mi], bhv, acc1[mi][ni], 0, 0, 0);
                    acc2[mi][ni] = __builtin_amdgcn_mfma_f32_16x16x32_f16(
                        ah[mi], blv, acc2[mi][ni], 0, 0, 0);
                    acc2[mi][ni] = __builtin_amdgcn_mfma_f32_16x16x32_f16(
                        al[mi], bhv, acc2[mi][ni], 0, 0, 0);
                }
            }
        }
        if (t + 1 < NT) {
            const int nb = cb ^ 1;
#pragma unroll
            for (int i = 0; i < 4; i++) {
                int m = ar + (i << 5);
                float x0 = g4.x * (av[i].x * ss1[i] - ss2[i]) + b4.x;
                float x1 = g4.y * (av[i].y * ss1[i] - ss2[i]) + b4.y;
                float x2 = g4.z * (av[i].z * ss1[i] - ss2[i]) + b4.z;
                float x3 = g4.w * (av[i].w * ss1[i] - ss2[i]) + b4.w;
                _Float16 h0 = (_Float16)x0, h1 = (_Float16)x1;
                _Float16 h2 = (_Float16)x2, h3 = (_Float16)x3;
                half4 hv = {h0, h1, h2, h3};
                half4 lv = {(_Float16)((x0 - (float)h0) * 4096.f),
                            (_Float16)((x1 - (float)h1) * 4096.f),
                            (_Float16)((x2 - (float)h2) * 4096.f),
                            (_Float16)((x3 - (float)h3) * 4096.f)};
                *(half4*)&Ah[nb][akg][m][aj] = hv;
                *(half4*)&Al[nb][akg][m][aj] = lv;
            }
            *(half8*)&Bh[nb][bkg][br][0] = wr0;
            *(half8*)&Bh[nb][bkg + 1][br][0] = wr1;
            *(half8*)&Bl[nb][bkg][br][0] = ur0;
            *(half8*)&Bl[nb][bkg + 1][br][0] = ur1;
        }
    }

    // epilogue: gelu + w2-fold, reduce over cols, atomicAdd per row
    const float S = 0.000244140625f;  // 2^-12
    float bz[4], wz[4];
#pragma unroll
    for (int ni = 0; ni < 4; ni++) {
        int col = n0 + wn + ni * 16 + lm;
        bz[ni] = b1[col];
        wz[ni] = w2[col];
    }
#pragma unroll
    for (int mi = 0; mi < 4; mi++) {
#pragma unroll
        for (int r = 0; r < 4; r++) {
            float p = 0.f;
#pragma unroll
            for (int ni = 0; ni < 4; ni++) {
                float val = acc1[mi][ni][r] + acc2[mi][ni][r] * S + bz[ni];
                p += geluf(val) * wz[ni];
            }
#pragma unroll
            for (int off = 1; off < 16; off <<= 1) p += __shfl_xor(p, off, 64);
            if (lm == 0) red[wm + mi * 16 + (lg << 2) + r][wv & 1] = p;
        }
    }
    __syncthreads();
    if (tid < 128) atomicAdd(&logits[m0 + tid], red[tid][0] + red[tid][1]);
}

// ---------------------------------------------------------------------------
// Detect + write: fp64 tail from fp32 logits; flag ambiguous batches.
// ---------------------------------------------------------------------------
__global__ __launch_bounds__(64) void finalize_detect_k(
    const float* __restrict__ logits, const float* __restrict__ sigma,
    float* __restrict__ out, int* __restrict__ cnt, int* __restrict__ list) {
    int b = blockIdx.x;
    int l = threadIdx.x;
    __shared__ double lgd[32], gsd[32];
    __shared__ int sb[2];
    if (l < 32) lgd[l] = (double)logits[(b << 5) + l];
    __syncthreads();
    if (l == 0) {
        int st, en, flag;
        tail_fp64(lgd, (double)sigma[0], gsd, &st, &en, &flag, EPS_DEC);
        sb[0] = st;
        sb[1] = en;
        if (flag) {
            int i = atomicAdd(cnt, 1);
            list[i] = b;
        }
    }
    __syncthreads();
    write_outputs(out, b, gsd, lgd, sb[0], sb[1], l);
}

// ---------------------------------------------------------------------------
// Gathered fp64 repair, stage 1: qa2 row per flagged batch.
// Weights staged through LDS in KT=8 slabs (cooperative float4 copies).
// ---------------------------------------------------------------------------
__global__ __launch_bounds__(256) void repair_qa_k(
    const float* __restrict__ qa, const float* __restrict__ qp_g,
    const float* __restrict__ qp_b, const float* __restrict__ qp_W,
    const float* __restrict__ qp_bias, const int* __restrict__ cnt,
    const int* __restrict__ list, double* __restrict__ qa2d) {
    int n = *cnt; if (n > CAP) n = CAP;
    int i = blockIdx.x;
    if (i >= n) return;
    int b = list[i];
    __shared__ double buf[768];
    __shared__ float Ws[8][768];
    __shared__ double sc[8];
    int tid = threadIdx.x;
    double s = 0., q = 0.;
    for (int j = tid; j < 768; j += 256) {
        double x = (double)qa[(size_t)b * 768 + j];
        buf[j] = x; s += x; q += x * x;
    }
#pragma unroll
    for (int m = 1; m < 64; m <<= 1) {
        s += __shfl_xor(s, m, 64);
        q += __shfl_xor(q, m, 64);
    }
    if ((tid & 63) == 0) { sc[tid >> 6] = s; sc[4 + (tid >> 6)] = q; }
    __syncthreads();
    double S = sc[0] + sc[1] + sc[2] + sc[3];
    double Q = sc[4] + sc[5] + sc[6] + sc[7];
    double mu = S * (1.0 / 768.0);
    double rs = rsqrt(Q * (1.0 / 768.0) - mu * mu + 1e-5);
    for (int j = tid; j < 768; j += 256)
        buf[j] = (buf[j] - mu) * rs * (double)qp_g[j] + (double)qp_b[j];
    __syncthreads();
    {
        double acc0 = 0., acc1 = 0., acc2 = 0.;
        for (int k0 = 0; k0 < 768; k0 += 8) {
            __syncthreads();   // prior-slab reads done before overwrite
            const float4* src = (const float4*)(qp_W + (size_t)k0 * 768);
#pragma unroll
            for (int t = 0; t < 6; t++)
                ((float4*)Ws)[tid + (t << 8)] = src[tid + (t << 8)];
            __syncthreads();
#pragma unroll
            for (int u = 0; u < 8; u++) {
                double a = buf[k0 + u];
                acc0 = fma(a, (double)Ws[u][tid], acc0);
                acc1 = fma(a, (double)Ws[u][tid + 256], acc1);
                acc2 = fma(a, (double)Ws[u][tid + 512], acc2);
            }
        }
        qa2d[(size_t)i * 768 + tid] = gelud(acc0 + (double)qp_bias[tid]);
        qa2d[(size_t)i * 768 + tid + 256] = gelud(acc1 + (double)qp_bias[tid + 256]);
        qa2d[(size_t)i * 768 + tid + 512] = gelud(acc2 + (double)qp_bias[tid + 512]);
    }
}

// ---------------------------------------------------------------------------
// Stage 2: v2 rows. 4 rows per block (8 blocks/batch), KT=8 LDS-staged W.
// ---------------------------------------------------------------------------
__global__ __launch_bounds__(256) void repair_v2_k(
    const float* __restrict__ v, const float* __restrict__ vp_g,
    const float* __restrict__ vp_b, const float* __restrict__ vp_W,
    const float* __restrict__ vp_bias, const int* __restrict__ cnt,
    const int* __restrict__ list, double* __restrict__ v2d) {
    int n = *cnt; if (n > CAP) n = CAP;
    int i = blockIdx.x >> 3, rg = blockIdx.x & 7;
    if (i >= n) return;
    int b = list[i];
    __shared__ double A[4][768];
    __shared__ float Ws[8][768];
    __shared__ double sc[8];
    int tid = threadIdx.x;
    for (int r = 0; r < 4; r++) {
        const float* vr = v + ((size_t)(b * 32 + rg * 4 + r)) * 768;
        double s = 0., q = 0.;
        for (int j = tid; j < 768; j += 256) {
            double x = (double)vr[j];
            A[r][j] = x; s += x; q += x * x;
        }
#pragma unroll
        for (int m = 1; m < 64; m <<= 1) {
            s += __shfl_xor(s, m, 64);
            q += __shfl_xor(q, m, 64);
        }
        if ((tid & 63) == 0) { sc[tid >> 6] = s; sc[4 + (tid >> 6)] = q; }
        __syncthreads();
        double S = sc[0] + sc[1] + sc[2] + sc[3];
        double Q = sc[4] + sc[5] + sc[6] + sc[7];
        double mu = S * (1.0 / 768.0);
        double rs = rsqrt(Q * (1.0 / 768.0) - mu * mu + 1e-5);
        for (int j = tid; j < 768; j += 256)
            A[r][j] = (A[r][j] - mu) * rs * (double)vp_g[j] + (double)vp_b[j];
        __syncthreads();
    }
    {
        double acc[3][4] = {};
        for (int k0 = 0; k0 < 768; k0 += 8) {
            __syncthreads();
            const float4* src = (const float4*)(vp_W + (size_t)k0 * 768);
#pragma unroll
            for (int t = 0; t < 6; t++)
                ((float4*)Ws)[tid + (t << 8)] = src[tid + (t << 8)];
            __syncthreads();
#pragma unroll
            for (int u = 0; u < 8; u++) {
                double w0 = (double)Ws[u][tid];
                double w1 = (double)Ws[u][tid + 256];
                double w2_ = (double)Ws[u][tid + 512];
#pragma unroll
                for (int r = 0; r < 4; r++) {
                    double a = A[r][k0 + u];
                    acc[0][r] = fma(a, w0, acc[0][r]);
                    acc[1][r] = fma(a, w1, acc[1][r]);
                    acc[2][r] = fma(a, w2_, acc[2][r]);
                }
            }
        }
        size_t base = (size_t)i * 32 + rg * 4;
#pragma unroll
        for (int jj = 0; jj < 3; jj++) {
            int j = tid + (jj << 8);
            double bias = (double)vp_bias[j];
#pragma unroll
            for (int r = 0; r < 4; r++)
                v2d[(base + r) * 768 + j] = gelud(acc[jj][r] + bias);
        }
    }
}

// ---------------------------------------------------------------------------
// Stage 3: gate + folded LN + h GEMM + logit. 4 rows per block
// (8 blocks/batch), KT=8 LDS-staged W1 (rows padded to 512 floats).
// ---------------------------------------------------------------------------
__global__ __launch_bounds__(256) void repair_h_k(
    const double* __restrict__ v2d, const double* __restrict__ qa2d,
    const float* __restrict__ gr_g, const float* __restrict__ gr_b,
    const float* __restrict__ gr_W1, const float* __restrict__ gr_b1,
    const float* __restrict__ gr_W2, const float* __restrict__ gr_b2,
    const int* __restrict__ cnt, const int* __restrict__ list,
    double* __restrict__ lgd_out) {
    int n = *cnt; if (n > CAP) n = CAP;
    int i = blockIdx.x >> 3, rg = blockIdx.x & 7;
    if (i >= n) return;
    __shared__ double A[4][768];
    __shared__ float Ws[8][512];   // 384 used, padded for safe idx
    __shared__ double sc[12];
    __shared__ double red[4][4];
    int tid = threadIdx.x;
    const double* qrow = qa2d + (size_t)i * 768;
    for (int r = 0; r < 4; r++) {
        const double* vr = v2d + ((size_t)i * 32 + rg * 4 + r) * 768;
        double s = 0., q = 0., dot = 0.;
        for (int j = tid; j < 768; j += 256) {
            double x = vr[j];
            A[r][j] = x; s += x; q += x * x; dot += x * qrow[j];
        }
#pragma unroll
        for (int m = 1; m < 64; m <<= 1) {
            s += __shfl_xor(s, m, 64);
            q += __shfl_xor(q, m, 64);
            dot += __shfl_xor(dot, m, 64);
        }
        if ((tid & 63) == 0) {
            int w = tid >> 6;
            sc[w] = s; sc[4 + w] = q; sc[8 + w] = dot;
        }
        __syncthreads();
        double S = sc[0] + sc[1] + sc[2] + sc[3];
        double Q = sc[4] + sc[5] + sc[6] + sc[7];
        double Dt = sc[8] + sc[9] + sc[10] + sc[11];
        double gate = tanh(Dt);
        double mu = gate * (S * (1.0 / 768.0));
        double var = gate * gate * (Q * (1.0 / 768.0)) - mu * mu;
        double rs = rsqrt(var + 1e-5);
        double s1v = gate * rs, s2v = mu * rs;
        for (int j = tid; j < 768; j += 256)
            A[r][j] = (double)gr_g[j] * (A[r][j] * s1v - s2v) + (double)gr_b[j];
        __syncthreads();
    }
    double part[4] = {};
    {
        const bool hi = (tid < 128);   // wave-uniform (waves 0,1 true; 2,3 false)
        double acc[2][4] = {};
        for (int k0 = 0; k0 < 768; k0 += 8) {
            __syncthreads();
            const float* src = gr_W1 + (size_t)k0 * 384;
            // 8x384 floats = 768 float4; thread loads 3 (row = f/96)
#pragma unroll
            for (int t = 0; t < 3; t++) {
                int f = tid + (t << 8);
                int kr = f / 96;
                int fc = (f - kr * 96) << 2;
                *(float4*)&Ws[kr][fc] = *(const float4*)&src[(size_t)kr * 384 + fc];
            }
            __syncthreads();
#pragma unroll
            for (int u = 0; u < 8; u++) {
                double w0 = (double)Ws[u][tid];
                double w1 = hi ? (double)Ws[u][tid + 256] : 0.;
#pragma unroll
                for (int r = 0; r < 4; r++) {
                    double a = A[r][k0 + u];
                    acc[0][r] = fma(a, w0, acc[0][r]);
                    acc[1][r] = fma(a, w1, acc[1][r]);
                }
            }
        }
        {
            double b1 = (double)gr_b1[tid], w2 = (double)gr_W2[tid];
#pragma unroll
            for (int r = 0; r < 4; r++) part[r] += gelud(acc[0][r] + b1) * w2;
        }
        if (hi) {
            double b1 = (double)gr_b1[tid + 256], w2 = (double)gr_W2[tid + 256];
#pragma unroll
            for (int r = 0; r < 4; r++) part[r] += gelud(acc[1][r] + b1) * w2;
        }
    }
#pragma unroll
    for (int r = 0; r < 4; r++)
#pragma unroll
        for (int m = 1; m < 64; m <<= 1) part[r] += __shfl_xor(part[r], m, 64);
    if ((tid & 63) == 0) {
        int w = tid >> 6;
#pragma unroll
        for (int r = 0; r < 4; r++) red[w][r] = part[r];
    }
    __syncthreads();
    if (tid < 4) {
        double t = red[0][tid] + red[1][tid] + red[2][tid] + red[3][tid] +
                   (double)gr_b2[0];
        lgd_out[(size_t)i * 32 + rg * 4 + tid] = t;
    }
}

// ---------------------------------------------------------------------------
// Stage 4: fp64 tail + output overwrite per flagged batch.
// ---------------------------------------------------------------------------
__global__ __launch_bounds__(64) void repair_fin_k(
    const double* __restrict__ lgd_in, const float* __restrict__ sigma,
    const int* __restrict__ cnt, const int* __restrict__ list,
    float* __restrict__ out) {
    int n = *cnt; if (n > CAP) n = CAP;
    int i = blockIdx.x;
    if (i >= n) return;
    int b = list[i];
    int l = threadIdx.x;
    __shared__ double lgd[32], gsd[32];
    __shared__ int sb[2];
    if (l < 32) lgd[l] = lgd_in[(size_t)i * 32 + l];
    __syncthreads();
    if (l == 0) {
        int st, en, flag;
        tail_fp64(lgd, (double)sigma[0], gsd, &st, &en, &flag, 0.);
        sb[0] = st;
        sb[1] = en;
    }
    __syncthreads();
    write_outputs(out, b, gsd, lgd, sb[0], sb[1], l);
}

// ---------------------------------------------------------------------------
// Fallback: monolithic fp64 repair for flagged batches beyond CAP (rare).
// ---------------------------------------------------------------------------
__global__ __launch_bounds__(256) void repair_slow_k(
    const float* __restrict__ v, const float* __restrict__ qa,
    const float* __restrict__ vp_g, const float* __restrict__ vp_b,
    const float* __restrict__ vp_W, const float* __restrict__ vp_bias,
    const float* __restrict__ qp_g, const float* __restrict__ qp_b,
    const float* __restrict__ qp_W, const float* __restrict__ qp_bias,
    const float* __restrict__ gr_g, const float* __restrict__ gr_b,
    const float* __restrict__ gr_W1, const float* __restrict__ gr_b1,
    const float* __restrict__ gr_W2, const float* __restrict__ gr_b2,
    const float* __restrict__ sigma, const int* __restrict__ cnt,
    const int* __restrict__ list, float* __restrict__ out) {
    __shared__ double qa2d[768];
    __shared__ double buf[768];
    __shared__ double v2r[768];
    __shared__ double hln[768];
    __shared__ double lgd[32], gsd[32];
    __shared__ double sc[12];
    __shared__ int sb[2];
    const int tid = threadIdx.x;
    const int n = *cnt;

    for (int ii = CAP + blockIdx.x; ii < n; ii += gridDim.x) {
        const int b = list[ii];
        double s = 0., q = 0.;
        for (int j = tid; j < 768; j += 256) {
            double x = (double)qa[(size_t)b * 768 + j];
            buf[j] = x; s += x; q += x * x;
        }
#pragma unroll
        for (int m = 1; m < 64; m <<= 1) {
            s += __shfl_xor(s, m, 64);
            q += __shfl_xor(q, m, 64);
        }
        if ((tid & 63) == 0) { sc[tid >> 6] = s; sc[4 + (tid >> 6)] = q; }
        __syncthreads();
        {
            double S = sc[0] + sc[1] + sc[2] + sc[3];
            double Q = sc[4] + sc[5] + sc[6] + sc[7];
            double mu = S * (1.0 / 768.0);
            double rs = rsqrt(Q * (1.0 / 768.0) - mu * mu + 1e-5);
            for (int j = tid; j < 768; j += 256)
                buf[j] = (buf[j] - mu) * rs * (double)qp_g[j] + (double)qp_b[j];
        }
        __syncthreads();
        for (int j = tid; j < 768; j += 256) {
            double acc = 0.;
#pragma unroll 8
            for (int k = 0; k < 768; k++)
                acc = fma(buf[k], (double)qp_W[(size_t)k * 768 + j], acc);
            qa2d[j] = gelud(acc + (double)qp_bias[j]);
        }
        __syncthreads();

        for (int r = 0; r < 32; r++) {
            const float* vr = v + ((size_t)(b * 32 + r)) * 768;
            s = 0.; q = 0.;
            for (int j = tid; j < 768; j += 256) {
                double x = (double)vr[j];
                buf[j] = x; s += x; q += x * x;
            }
#pragma unroll
            for (int m = 1; m < 64; m <<= 1) {
                s += __shfl_xor(s, m, 64);
                q += __shfl_xor(q, m, 64);
            }
            if ((tid & 63) == 0) { sc[tid >> 6] = s; sc[4 + (tid >> 6)] = q; }
            __syncthreads();
            {
                double S = sc[0] + sc[1] + sc[2] + sc[3];
                double Q = sc[4] + sc[5] + sc[6] + sc[7];
                double mu = S * (1.0 / 768.0);
                double rs = rsqrt(Q * (1.0 / 768.0) - mu * mu + 1e-5);
                for (int j = tid; j < 768; j += 256)
                    buf[j] = (buf[j] - mu) * rs * (double)vp_g[j] + (double)vp_b[j];
            }
            __syncthreads();
            for (int j = tid; j < 768; j += 256) {
                double acc = 0.;
#pragma unroll 8
                for (int k = 0; k < 768; k++)
                    acc = fma(buf[k], (double)vp_W[(size_t)k * 768 + j], acc);
                v2r[j] = gelud(acc + (double)vp_bias[j]);
            }
            __syncthreads();
            double dot = 0.;
            s = 0.; q = 0.;
            for (int j = tid; j < 768; j += 256) {
                double x = v2r[j];
                dot += x * qa2d[j]; s += x; q += x * x;
            }
#pragma unroll
            for (int m = 1; m < 64; m <<= 1) {
                dot += __shfl_xor(dot, m, 64);
                s += __shfl_xor(s, m, 64);
                q += __shfl_xor(q, m, 64);
            }
            if ((tid & 63) == 0) {
                sc[tid >> 6] = s;
                sc[4 + (tid >> 6)] = q;
                sc[8 + (tid >> 6)] = dot;
            }
            __syncthreads();
            {
                double S = sc[0] + sc[1] + sc[2] + sc[3];
                double Q = sc[4] + sc[5] + sc[6] + sc[7];
                double Dt = sc[8] + sc[9] + sc[10] + sc[11];
                double gate = tanh(Dt);
                double mu = gate * (S * (1.0 / 768.0));
                double var = gate * gate * (Q * (1.0 / 768.0)) - mu * mu;
                double rs = rsqrt(var + 1e-5);
                double s1v = gate * rs, s2v = mu * rs;
                for (int j = tid; j < 768; j += 256)
                    hln[j] = (double)gr_g[j] * (v2r[j] * s1v - s2v) + (double)gr_b[j];
            }
            __syncthreads();
            double part = 0.;
            for (int j = tid; j < 384; j += 256) {
                double acc = 0.;
#pragma unroll 8
                for (int k = 0; k < 768; k++)
                    acc = fma(hln[k], (double)gr_W1[(size_t)k * 384 + j], acc);
                part += gelud(acc + (double)gr_b1[j]) * (double)gr_W2[j];
            }
#pragma unroll
            for (int m = 1; m < 64; m <<= 1) part += __shfl_xor(part, m, 64);
            if ((tid & 63) == 0) sc[tid >> 6] = part;
            __syncthreads();
            if (tid == 0) lgd[r] = sc[0] + sc[1] + sc[2] + sc[3] + (double)gr_b2[0];
            __syncthreads();
        }
        if (tid == 0) {
            int st, en, flag;
            tail_fp64(lgd, (double)sigma[0], gsd, &st, &en, &flag, 0.);
            sb[0] = st;
            sb[1] = en;
        }
        __syncthreads();
        write_outputs(out, b, gsd, lgd, sb[0], sb[1], tid);
        __syncthreads();
    }
}

// ---------------------------------------------------------------------------
extern "C" void kernel_launch(void* const* d_in, const int* in_sizes, int n_in,
                              void* d_out, int out_size, void* d_ws, size_t ws_size,
                              hipStream_t stream) {
    (void)in_sizes; (void)n_in; (void)out_size;
    const float* v = (const float*)d_in[0];
    const float* qa = (const float*)d_in[1];
    const float* vp_g = (const float*)d_in[2];
    const float* vp_b = (const float*)d_in[3];
    const float* vp_W = (const float*)d_in[4];
    const float* vp_bias = (const float*)d_in[5];
    const float* qp_g = (const float*)d_in[6];
    const float* qp_b = (const float*)d_in[7];
    const float* qp_W = (const float*)d_in[8];
    const float* qp_bias = (const float*)d_in[9];
    const float* gr_g = (const float*)d_in[10];
    const float* gr_b = (const float*)d_in[11];
    const float* gr_W1 = (const float*)d_in[12];
    const float* gr_b1 = (const float*)d_in[13];
    const float* gr_W2 = (const float*)d_in[14];
    const float* gr_b2 = (const float*)d_in[15];
    const float* sigma = (const float*)d_in[16];
    float* out = (float*)d_out;

    // ws: [cnt(8 ints) | list(4096 ints) | pad to 32KB] [fp64 repair buffers]
    //     [fp16 split-transposed weights] [fp32 main-path scratch]
    int* cnt = (int*)d_ws;
    int* list = cnt + 8;
    hipMemsetAsync(d_ws, 0, 32, stream);
    double* qa2d = (double*)((char*)d_ws + 32768);
    double* v2d = qa2d + (size_t)CAP * 768;
    double* lgdr = v2d + (size_t)CAP * 32 * 768;
    unsigned short* qWhi = (unsigned short*)(lgdr + (size_t)CAP * 32);
    unsigned short* qWlo = qWhi + (size_t)DD * DD;
    unsigned short* vWhi = qWlo + (size_t)DD * DD;
    unsigned short* vWlo = vWhi + (size_t)DD * DD;
    unsigned short* w1hi = vWlo + (size_t)DD * DD;
    unsigned short* w1lo = w1hi + (size_t)DD * HH;
    float* p = (float*)(w1lo + (size_t)DD * HH);

    size_t head_floats = (size_t)((char*)p - (char*)d_ws) / 4;
    float* qa_mean = p; p += BSZ;
    float* qa_rstd = p; p += BSZ;
    float* qa2 = p; p += (size_t)BSZ * DD;
    float* logits = p; p += (size_t)BSZ * LL;

    size_t fixed = head_floats + (size_t)BSZ * 2 + (size_t)BSZ * DD + (size_t)BSZ * LL;
    int bpc = 1024;
    while (bpc > 32) {
        size_t rows = (size_t)bpc * LL;
        size_t need = fixed + rows * 4 + rows * DD;
        if (need * sizeof(float) <= ws_size) break;
        bpc >>= 1;
    }
    size_t rows = (size_t)bpc * LL;
    float* v_mean = p; p += rows;
    float* v_rstd = p; p += rows;
    float* s1 = p; p += rows;
    float* s2 = p; p += rows;
    float* v2 = p; p += rows * DD;

    // one-time: split+transpose weights to fp16 hi/lo
    wsplit_k<<<dim3(12, 12), dim3(256), 0, stream>>>(qp_W, qWhi, qWlo, DD);
    wsplit_k<<<dim3(12, 12), dim3(256), 0, stream>>>(vp_W, vWhi, vWlo, DD);
    wsplit_k<<<dim3(6, 12), dim3(256), 0, stream>>>(gr_W1, w1hi, w1lo, HH);

    // qa path (once)
    row_stats_k<<<dim3((unsigned)((BSZ * 64) / 256)), dim3(256), 0, stream>>>(
        qa, qa_mean, qa_rstd, BSZ);
    gemm_ln_gelu_k<<<dim3(BSZ / 128, DD / 128), dim3(256), 0, stream>>>(
        qa, qa_mean, qa_rstd, qp_g, qp_b, qWhi, qWlo, qp_bias, qa2);

    int nch = BSZ / bpc;
    for (int c = 0; c < nch; c++) {
        int rowbase = c * (int)rows;
        const float* vchunk = v + (size_t)rowbase * DD;
        row_stats_k<<<dim3((unsigned)((rows * 64) / 256)), dim3(256), 0, stream>>>(
            vchunk, v_mean, v_rstd, (int)rows);
        gemm_ln_gelu_k<<<dim3((unsigned)(rows / 128), DD / 128), dim3(256), 0, stream>>>(
            vchunk, v_mean, v_rstd, vp_g, vp_b, vWhi, vWlo, vp_bias, v2);
        gate_stats_k<<<dim3((unsigned)((rows * 64) / 256)), dim3(256), 0, stream>>>(
            v2, qa2, s1, s2, logits, gr_b2, rowbase, (int)rows);
        gemm_h_logits_k<<<dim3((unsigned)(rows / 128), HH / 128), dim3(256), 0, stream>>>(
            v2, s1, s2, gr_g, gr_b, w1hi, w1lo, gr_b1, gr_W2, logits + rowbase);
    }
    finalize_detect_k<<<dim3(BSZ), dim3(64), 0, stream>>>(logits, sigma, out, cnt, list);
    // gathered fp64 repair for flagged batches (<= CAP)
    repair_qa_k<<<dim3(CAP), dim3(256), 0, stream>>>(
        qa, qp_g, qp_b, qp_W, qp_bias, cnt, list, qa2d);
    repair_v2_k<<<dim3(CAP * 8), dim3(256), 0, stream>>>(
        v, vp_g, vp_b, vp_W, vp_bias, cnt, list, v2d);
    repair_h_k<<<dim3(CAP * 8), dim3(256), 0, stream>>>(
        v2d, qa2d, gr_g, gr_b, gr_W1, gr_b1, gr_W2, gr_b2, cnt, list, lgdr);
    repair_fin_k<<<dim3(CAP), dim3(64), 0, stream>>>(lgdr, sigma, cnt, list, out);
    // overflow fallback (no-op unless > CAP batches flagged)
    repair_slow_k<<<dim3(256), dim3(256), 0, stream>>>(
        v, qa, vp_g, vp_b, vp_W, vp_bias, qp_g, qp_b, qp_W, qp_bias,
        gr_g, gr_b, gr_W1, gr_b1, gr_W2, gr_b2, sigma, cnt, list, out);
}

// Round 10
// 2339.362 us; speedup vs baseline: 1.3493x; 1.3493x over previous
//
#include <hip/hip_runtime.h>
#include <math.h>

#define DD 768
#define HH 384
#define LL 32
#define BSZ 4096
#define CAP 256          // max batches handled by fast gathered fp64 repair
#define EPS_DEC 4e-7     // decision margin (fp16x2-MFMA path gs error ~1e-8)

typedef _Float16 half8 __attribute__((ext_vector_type(8)));
typedef _Float16 half4 __attribute__((ext_vector_type(4)));
typedef float floatx4 __attribute__((ext_vector_type(4)));

static __device__ __forceinline__ float geluf(float x) {
    return 0.5f * x * (1.0f + erff(x * 0.70710678118654752440f));
}
static __device__ __forceinline__ double gelud(double x) {
    return 0.5 * x * (1.0 + erf(x * 0.70710678118654752440));
}

// ---------------------------------------------------------------------------
// Serial fp64 tail. lgd[32] -> gsd[32], st/en; flag if any decision margin
// < eps (eps=0 disables flagging for the repair path).
// ---------------------------------------------------------------------------
static __device__ void tail_fp64(const double* lgd, double sigma, double* gsd,
                                 int* pst, int* pen, int* pflag, double eps) {
    double kern[5];
    {
        double inv = 1.0 / sigma, ssum = 0.;
#pragma unroll
        for (int j = 0; j < 5; j++) {
            double t = (double)(j - 2) * inv;
            kern[j] = exp(-0.5 * t * t);
            ssum += kern[j];
        }
#pragma unroll
        for (int j = 0; j < 5; j++) kern[j] /= ssum;
    }
    double kp[32];
    {
        double mx = lgd[0];
        for (int i = 1; i < 32; i++) mx = fmax(mx, lgd[i]);
        double sum = 0.;
        for (int i = 0; i < 32; i++) { kp[i] = exp(lgd[i] - mx); sum += kp[i]; }
        for (int i = 0; i < 32; i++) kp[i] /= sum;
    }
    double sm[32];
    for (int i = 0; i < 32; i++) {
        double a = 0.;
#pragma unroll
        for (int j = 0; j < 5; j++) {
            int t = i + j - 2;
            if (t >= 0 && t < 32) a += kern[j] * kp[t];
        }
        sm[i] = a;
    }
    {
        double mx = sm[0];
        for (int i = 1; i < 32; i++) mx = fmax(mx, sm[i]);
        double sum = 0.;
        for (int i = 0; i < 32; i++) { gsd[i] = exp(sm[i] - mx); sum += gsd[i]; }
        for (int i = 0; i < 32; i++) gsd[i] /= sum;
    }
    int am = 0;
    double bv = gsd[0];
    for (int i = 1; i < 32; i++)
        if (gsd[i] > bv) { bv = gsd[i]; am = i; }
    int flag = 0;
    if (eps > 0.) {
        double second = -INFINITY;
        for (int i = 0; i < 32; i++)
            if (i != am && gsd[i] > second) second = gsd[i];
        if (bv - second < eps) flag = 1;
    }
    double cs[33];
    cs[0] = 0.;
    double c = 0.;
    for (int i = 0; i < 32; i++) { c += gsd[i]; cs[i + 1] = c; }
    double best = -INFINITY;
    int bs0 = 0, be0 = 0;
    const int wsz[3] = {1, 3, 5};
    for (int wi = 0; wi < 3; wi++) {
        int w = wsz[wi];
        for (int st = 0; st <= 32 - w; st++) {
            if (am >= st && am < st + w) {
                double sc = cs[st + w] - cs[st];
                if (sc > best) { best = sc; bs0 = st; be0 = st + w; }
            }
        }
    }
    if (eps > 0.) {
        int near = 0;
        for (int wi = 0; wi < 3; wi++) {
            int w = wsz[wi];
            for (int st = 0; st <= 32 - w; st++) {
                if (am >= st && am < st + w) {
                    double sc = cs[st + w] - cs[st];
                    if (sc > best - eps) near++;
                }
            }
        }
        if (near >= 2) flag = 1;
    }
    *pst = bs0;
    *pen = be0;
    *pflag = flag;
}

static __device__ __forceinline__ void write_outputs(float* out, int b,
                                                     const double* gsd,
                                                     const double* lgd,
                                                     int st0, int en0, int l) {
    float* o_gs = out;
    float* o_idx = out + 131072;
    float* o_st = out + 139264;
    float* o_et = out + 143360;
    float* o_mask = out + 147456;
    float* o_ok = out + 278528;
    if (l < 32) {
        o_gs[(b << 5) + l] = (float)gsd[l];
        o_mask[(b << 5) + l] = (l >= st0 && l <= en0) ? 1.f : 0.f;
        o_ok[(b << 5) + l] = (float)lgd[l];
    }
    if (l == 0) {
        o_idx[(b << 1)] = (float)st0;
        o_idx[(b << 1) + 1] = (float)en0;
        o_st[b] = (float)((double)st0 / 31.0);
        o_et[b] = (float)((double)en0 / 31.0);
    }
}

// ---------------------------------------------------------------------------
// Per-row mean / rstd over 768 floats (double accum). One wave per row.
// ---------------------------------------------------------------------------
__global__ __launch_bounds__(256) void row_stats_k(const float* __restrict__ X,
                                                   float* __restrict__ mean,
                                                   float* __restrict__ rstd,
                                                   int nrows) {
    int w = (int)((blockIdx.x * blockDim.x + threadIdx.x) >> 6);
    int lane = threadIdx.x & 63;
    if (w >= nrows) return;
    const float* row = X + (size_t)w * DD;
    double s = 0., q = 0.;
#pragma unroll
    for (int i = 0; i < 3; i++) {
        float4 v = *(const float4*)(row + ((lane + (i << 6)) << 2));
        double a = v.x, b = v.y, c = v.z, d = v.w;
        s += a + b + c + d;
        q += a * a + b * b + c * c + d * d;
    }
#pragma unroll
    for (int m = 1; m < 64; m <<= 1) {
        s += __shfl_xor(s, m, 64);
        q += __shfl_xor(q, m, 64);
    }
    if (lane == 0) {
        double mu = s * (1.0 / 768.0);
        double var = q * (1.0 / 768.0) - mu * mu;
        mean[w] = (float)mu;
        rstd[w] = (float)rsqrt(var + 1e-5);
    }
}

// ---------------------------------------------------------------------------
// Split fp32 W[k][n] (768 x N) into fp16 hi/lo, TRANSPOSED to [n][768].
// lo = fp16(x - hi) UNSCALED (magnitude ~2^-12; fp16 normal/subnormal range
// covers it). Cross MFMA products then arrive pre-scaled -> single
// accumulator in the GEMMs (halves accumulator VGPRs).
// Grid: (N/64, 768/64).
// ---------------------------------------------------------------------------
__global__ __launch_bounds__(256) void wsplit_k(const float* __restrict__ W,
                                                unsigned short* __restrict__ hiT,
                                                unsigned short* __restrict__ loT,
                                                int N) {
    __shared__ float t[64][65];
    const int tid = threadIdx.x;
    const int n0 = blockIdx.x << 6, k0 = blockIdx.y << 6;
    const int kr = tid >> 4, nc = (tid & 15) << 2;
#pragma unroll
    for (int i = 0; i < 4; i++) {
        float4 v = *(const float4*)&W[(size_t)(k0 + kr + (i << 4)) * N + n0 + nc];
        t[kr + (i << 4)][nc] = v.x;
        t[kr + (i << 4)][nc + 1] = v.y;
        t[kr + (i << 4)][nc + 2] = v.z;
        t[kr + (i << 4)][nc + 3] = v.w;
    }
    __syncthreads();
    const int nr = tid >> 2, kc = (tid & 3) << 4;
    half8 hv0 = {}, hv1 = {}, lv0 = {}, lv1 = {};
#pragma unroll
    for (int j = 0; j < 8; j++) {
        float x = t[kc + j][nr];
        _Float16 h = (_Float16)x;
        hv0[j] = h;
        lv0[j] = (_Float16)(x - (float)h);
    }
#pragma unroll
    for (int j = 0; j < 8; j++) {
        float x = t[kc + 8 + j][nr];
        _Float16 h = (_Float16)x;
        hv1[j] = h;
        lv1[j] = (_Float16)(x - (float)h);
    }
    size_t base = (size_t)(n0 + nr) * DD + k0 + kc;
    *(half8*)&hiT[base] = hv0;
    *(half8*)&hiT[base + 8] = hv1;
    *(half8*)&loT[base] = lv0;
    *(half8*)&loT[base + 8] = lv1;
}

// ---------------------------------------------------------------------------
// Out = gelu( LN(A) @ W + bias ) via fp16x2 split-precision MFMA.
// 128x128 tile, 4 waves (2x2), 64x64/wave, BK=32, mfma_f32_16x16x32_f16.
// Round-8 verified schedule (single-buffered, 2 barriers/tile).
// SINGLE fused accumulator: lo residuals are unscaled, so the three
// products (hi*hi, hi*lo, lo*hi) accumulate directly -> 64 fewer VGPRs,
// higher occupancy (the round-8 limiter).
// ---------------------------------------------------------------------------
__global__ __launch_bounds__(256) void gemm_ln_gelu_k(
    const float* __restrict__ A, const float* __restrict__ mean,
    const float* __restrict__ rstd, const float* __restrict__ lng,
    const float* __restrict__ lnb, const unsigned short* __restrict__ WhiT,
    const unsigned short* __restrict__ WloT, const float* __restrict__ bias,
    float* __restrict__ Out) {
    __shared__ _Float16 Ah[4][128][8];
    __shared__ _Float16 Al[4][128][8];
    __shared__ _Float16 Bh[4][128][8];
    __shared__ _Float16 Bl[4][128][8];
    const int tid = threadIdx.x;
    const int m0 = blockIdx.x << 7;
    const int n0 = blockIdx.y << 7;
    const int l = tid & 63;
    const int wv = tid >> 6;
    const int wm = (wv >> 1) << 6;      // wave row base 0/64
    const int wn = (wv & 1) << 6;       // wave col base 0/64
    const int lm = l & 15, lg = l >> 4;
    const int ar = tid >> 3;            // rows ar, ar+32, ar+64, ar+96
    const int k4 = (tid & 7) << 2;      // k offset 0..28
    const int akg = k4 >> 3, aj = k4 & 7;
    const int br = tid >> 1;            // n-row 0..127
    const int bh16 = (tid & 1) << 4;    // k offset 0/16
    const int bkg = bh16 >> 3;          // 0 or 2

    float mu[4], rs[4];
#pragma unroll
    for (int i = 0; i < 4; i++) {
        mu[i] = mean[m0 + ar + (i << 5)];
        rs[i] = rstd[m0 + ar + (i << 5)];
    }
    floatx4 acc[4][4] = {};
    const float* Ab = A + (size_t)m0 * DD;
    const unsigned short* WhB = WhiT + (size_t)n0 * DD;
    const unsigned short* WlB = WloT + (size_t)n0 * DD;

    for (int kb = 0; kb < DD; kb += 32) {
        __syncthreads();
        // ---- stage A: fp32 load, LN, split hi/lo (lo unscaled) ----
        {
            float4 g4 = *(const float4*)&lng[kb + k4];
            float4 b4 = *(const float4*)&lnb[kb + k4];
#pragma unroll
            for (int i = 0; i < 4; i++) {
                int m = ar + (i << 5);
                float4 av = *(const float4*)&Ab[(size_t)m * DD + kb + k4];
                float x0 = (av.x - mu[i]) * rs[i] * g4.x + b4.x;
                float x1 = (av.y - mu[i]) * rs[i] * g4.y + b4.y;
                float x2 = (av.z - mu[i]) * rs[i] * g4.z + b4.z;
                float x3 = (av.w - mu[i]) * rs[i] * g4.w + b4.w;
                _Float16 h0 = (_Float16)x0, h1 = (_Float16)x1;
                _Float16 h2 = (_Float16)x2, h3 = (_Float16)x3;
                half4 hv = {h0, h1, h2, h3};
                half4 lv = {(_Float16)(x0 - (float)h0),
                            (_Float16)(x1 - (float)h1),
                            (_Float16)(x2 - (float)h2),
                            (_Float16)(x3 - (float)h3)};
                *(half4*)&Ah[akg][m][aj] = hv;
                *(half4*)&Al[akg][m][aj] = lv;
            }
        }
        // ---- stage B: pre-split fp16 copy ----
        {
            const unsigned short* sh = WhB + (size_t)br * DD + kb + bh16;
            const unsigned short* sl = WlB + (size_t)br * DD + kb + bh16;
            half8 w0 = *(const half8*)sh;
            half8 w1 = *(const half8*)(sh + 8);
            half8 u0 = *(const half8*)sl;
            half8 u1 = *(const half8*)(sl + 8);
            *(half8*)&Bh[bkg][br][0] = w0;
            *(half8*)&Bh[bkg + 1][br][0] = w1;
            *(half8*)&Bl[bkg][br][0] = u0;
            *(half8*)&Bl[bkg + 1][br][0] = u1;
        }
        __syncthreads();
        // ---- MFMA compute: all three products into one accumulator ----
        half8 ah[4], al[4];
#pragma unroll
        for (int mi = 0; mi < 4; mi++) {
            ah[mi] = *(const half8*)&Ah[lg][wm + mi * 16 + lm][0];
            al[mi] = *(const half8*)&Al[lg][wm + mi * 16 + lm][0];
        }
#pragma unroll
        for (int ni = 0; ni < 4; ni++) {
            half8 bhv = *(const half8*)&Bh[lg][wn + ni * 16 + lm][0];
            half8 blv = *(const half8*)&Bl[lg][wn + ni * 16 + lm][0];
#pragma unroll
            for (int mi = 0; mi < 4; mi++) {
                acc[mi][ni] = __builtin_amdgcn_mfma_f32_16x16x32_f16(
                    ah[mi], bhv, acc[mi][ni], 0, 0, 0);
                acc[mi][ni] = __builtin_amdgcn_mfma_f32_16x16x32_f16(
                    ah[mi], blv, acc[mi][ni], 0, 0, 0);
                acc[mi][ni] = __builtin_amdgcn_mfma_f32_16x16x32_f16(
                    al[mi], bhv, acc[mi][ni], 0, 0, 0);
            }
        }
    }

    // epilogue: bias, gelu, store
#pragma unroll
    for (int ni = 0; ni < 4; ni++) {
        float bz = bias[n0 + wn + ni * 16 + lm];
#pragma unroll
        for (int mi = 0; mi < 4; mi++) {
#pragma unroll
            for (int r = 0; r < 4; r++) {
                float val = acc[mi][ni][r] + bz;
                int row = m0 + wm + mi * 16 + (lg << 2) + r;
                Out[(size_t)row * DD + n0 + wn + ni * 16 + lm] = geluf(val);
            }
        }
    }
}

// ---------------------------------------------------------------------------
// gate = tanh(v2 . qa2[batch]); fold LN(v2*gate) into s1,s2 (double accum).
// ---------------------------------------------------------------------------
__global__ __launch_bounds__(256) void gate_stats_k(
    const float* __restrict__ V2, const float* __restrict__ qa2,
    float* __restrict__ s1, float* __restrict__ s2,
    float* __restrict__ logits, const float* __restrict__ b2,
    int rowbase, int nrows) {
    int r = (int)((blockIdx.x * blockDim.x + threadIdx.x) >> 6);
    int lane = threadIdx.x & 63;
    if (r >= nrows) return;
    const float* vr = V2 + (size_t)r * DD;
    const float* qr = qa2 + (size_t)((rowbase + r) >> 5) * DD;
    double dot = 0., s = 0., q = 0.;
#pragma unroll
    for (int i = 0; i < 3; i++) {
        int idx = (lane + (i << 6)) << 2;
        float4 a = *(const float4*)(vr + idx);
        float4 b = *(const float4*)(qr + idx);
        double ax = a.x, ay = a.y, az = a.z, aw = a.w;
        dot += ax * b.x + ay * b.y + az * b.z + aw * b.w;
        s += ax + ay + az + aw;
        q += ax * ax + ay * ay + az * az + aw * aw;
    }
#pragma unroll
    for (int m = 1; m < 64; m <<= 1) {
        dot += __shfl_xor(dot, m, 64);
        s += __shfl_xor(s, m, 64);
        q += __shfl_xor(q, m, 64);
    }
    double gate = tanh(dot);
    double mu = gate * (s * (1.0 / 768.0));
    double var = gate * gate * (q * (1.0 / 768.0)) - mu * mu;
    double rs = rsqrt(var + 1e-5);
    if (lane == 0) {
        s1[r] = (float)(gate * rs);
        s2[r] = (float)(mu * rs);
        logits[rowbase + r] = b2[0];
    }
}

// ---------------------------------------------------------------------------
// logits += gelu( foldedLN(v2) @ W1 + b1 ) @ w2 via fp16x2 MFMA.
// Round-8 schedule + fused single accumulator (as gemm_ln_gelu_k).
// ---------------------------------------------------------------------------
__global__ __launch_bounds__(256) void gemm_h_logits_k(
    const float* __restrict__ V2, const float* __restrict__ s1,
    const float* __restrict__ s2, const float* __restrict__ gg,
    const float* __restrict__ gb, const unsigned short* __restrict__ WhiT,
    const unsigned short* __restrict__ WloT, const float* __restrict__ b1,
    const float* __restrict__ w2, float* __restrict__ logits) {
    __shared__ _Float16 Ah[4][128][8];
    __shared__ _Float16 Al[4][128][8];
    __shared__ _Float16 Bh[4][128][8];
    __shared__ _Float16 Bl[4][128][8];
    __shared__ float red[128][2];
    const int tid = threadIdx.x;
    const int m0 = blockIdx.x << 7;
    const int n0 = blockIdx.y << 7;
    const int l = tid & 63;
    const int wv = tid >> 6;
    const int wm = (wv >> 1) << 6;
    const int wn = (wv & 1) << 6;
    const int lm = l & 15, lg = l >> 4;
    const int ar = tid >> 3;
    const int k4 = (tid & 7) << 2;
    const int akg = k4 >> 3, aj = k4 & 7;
    const int br = tid >> 1;
    const int bh16 = (tid & 1) << 4;
    const int bkg = bh16 >> 3;

    float ss1[4], ss2[4];
#pragma unroll
    for (int i = 0; i < 4; i++) {
        ss1[i] = s1[m0 + ar + (i << 5)];
        ss2[i] = s2[m0 + ar + (i << 5)];
    }
    floatx4 acc[4][4] = {};
    const float* Ab = V2 + (size_t)m0 * DD;
    const unsigned short* WhB = WhiT + (size_t)n0 * DD;
    const unsigned short* WlB = WloT + (size_t)n0 * DD;

    for (int kb = 0; kb < DD; kb += 32) {
        __syncthreads();
        {
            float4 g4 = *(const float4*)&gg[kb + k4];
            float4 b4 = *(const float4*)&gb[kb + k4];
#pragma unroll
            for (int i = 0; i < 4; i++) {
                int m = ar + (i << 5);
                float4 av = *(const float4*)&Ab[(size_t)m * DD + kb + k4];
                float x0 = g4.x * (av.x * ss1[i] - ss2[i]) + b4.x;
                float x1 = g4.y * (av.y * ss1[i] - ss2[i]) + b4.y;
                float x2 = g4.z * (av.z * ss1[i] - ss2[i]) + b4.z;
                float x3 = g4.w * (av.w * ss1[i] - ss2[i]) + b4.w;
                _Float16 h0 = (_Float16)x0, h1 = (_Float16)x1;
                _Float16 h2 = (_Float16)x2, h3 = (_Float16)x3;
                half4 hv = {h0, h1, h2, h3};
                half4 lv = {(_Float16)(x0 - (float)h0),
                            (_Float16)(x1 - (float)h1),
                            (_Float16)(x2 - (float)h2),
                            (_Float16)(x3 - (float)h3)};
                *(half4*)&Ah[akg][m][aj] = hv;
                *(half4*)&Al[akg][m][aj] = lv;
            }
        }
        {
            const unsigned short* sh = WhB + (size_t)br * DD + kb + bh16;
            const unsigned short* sl = WlB + (size_t)br * DD + kb + bh16;
            half8 w0 = *(const half8*)sh;
            half8 w1 = *(const half8*)(sh + 8);
            half8 u0 = *(const half8*)sl;
            half8 u1 = *(const half8*)(sl + 8);
            *(half8*)&Bh[bkg][br][0] = w0;
            *(half8*)&Bh[bkg + 1][br][0] = w1;
            *(half8*)&Bl[bkg][br][0] = u0;
            *(half8*)&Bl[bkg + 1][br][0] = u1;
        }
        __syncthreads();
        half8 ah[4], al[4];
#pragma unroll
        for (int mi = 0; mi < 4; mi++) {
            ah[mi] = *(const half8*)&Ah[lg][wm + mi * 16 + lm][0];
            al[mi] = *(const half8*)&Al[lg][wm + mi * 16 + lm][0];
        }
#pragma unroll
        for (int ni = 0; ni < 4; ni++) {
            half8 bhv = *(const half8*)&Bh[lg][wn + ni * 16 + lm][0];
            half8 blv = *(const half8*)&Bl[lg][wn + ni * 16 + lm][0];
#pragma unroll
            for (int mi = 0; mi < 4; mi++) {
                acc[mi][ni] = __builtin_amdgcn_mfma_f32_16x16x32_f16(
                    ah[mi], bhv, acc[mi][ni], 0, 0, 0);
                acc[mi][ni] = __builtin_amdgcn_mfma_f32_16x16x32_f16(
                    ah[mi], blv, acc[mi][ni], 0, 0, 0);
                acc[mi][ni] = __builtin_amdgcn_mfma_f32_16x16x32_f16(
                    al[mi], bhv, acc[mi][ni], 0, 0, 0);
            }
        }
    }

    // epilogue: gelu + w2-fold, reduce over cols, atomicAdd per row
    float bz[4], wz[4];
#pragma unroll
    for (int ni = 0; ni < 4; ni++) {
        int col = n0 + wn + ni * 16 + lm;
        bz[ni] = b1[col];
        wz[ni] = w2[col];
    }
#pragma unroll
    for (int mi = 0; mi < 4; mi++) {
#pragma unroll
        for (int r = 0; r < 4; r++) {
            float p = 0.f;
#pragma unroll
            for (int ni = 0; ni < 4; ni++) {
                float val = acc[mi][ni][r] + bz[ni];
                p += geluf(val) * wz[ni];
            }
#pragma unroll
            for (int off = 1; off < 16; off <<= 1) p += __shfl_xor(p, off, 64);
            if (lm == 0) red[wm + mi * 16 + (lg << 2) + r][wv & 1] = p;
        }
    }
    __syncthreads();
    if (tid < 128) atomicAdd(&logits[m0 + tid], red[tid][0] + red[tid][1]);
}

// ---------------------------------------------------------------------------
// Detect + write: fp64 tail from fp32 logits; flag ambiguous batches.
// ---------------------------------------------------------------------------
__global__ __launch_bounds__(64) void finalize_detect_k(
    const float* __restrict__ logits, const float* __restrict__ sigma,
    float* __restrict__ out, int* __restrict__ cnt, int* __restrict__ list) {
    int b = blockIdx.x;
    int l = threadIdx.x;
    __shared__ double lgd[32], gsd[32];
    __shared__ int sb[2];
    if (l < 32) lgd[l] = (double)logits[(b << 5) + l];
    __syncthreads();
    if (l == 0) {
        int st, en, flag;
        tail_fp64(lgd, (double)sigma[0], gsd, &st, &en, &flag, EPS_DEC);
        sb[0] = st;
        sb[1] = en;
        if (flag) {
            int i = atomicAdd(cnt, 1);
            list[i] = b;
        }
    }
    __syncthreads();
    write_outputs(out, b, gsd, lgd, sb[0], sb[1], l);
}

// ---------------------------------------------------------------------------
// Gathered fp64 repair, stage 1: qa2 row per flagged batch.
// Weights staged through LDS in KT=8 slabs (cooperative float4 copies).
// ---------------------------------------------------------------------------
__global__ __launch_bounds__(256) void repair_qa_k(
    const float* __restrict__ qa, const float* __restrict__ qp_g,
    const float* __restrict__ qp_b, const float* __restrict__ qp_W,
    const float* __restrict__ qp_bias, const int* __restrict__ cnt,
    const int* __restrict__ list, double* __restrict__ qa2d) {
    int n = *cnt; if (n > CAP) n = CAP;
    int i = blockIdx.x;
    if (i >= n) return;
    int b = list[i];
    __shared__ double buf[768];
    __shared__ float Ws[8][768];
    __shared__ double sc[8];
    int tid = threadIdx.x;
    double s = 0., q = 0.;
    for (int j = tid; j < 768; j += 256) {
        double x = (double)qa[(size_t)b * 768 + j];
        buf[j] = x; s += x; q += x * x;
    }
#pragma unroll
    for (int m = 1; m < 64; m <<= 1) {
        s += __shfl_xor(s, m, 64);
        q += __shfl_xor(q, m, 64);
    }
    if ((tid & 63) == 0) { sc[tid >> 6] = s; sc[4 + (tid >> 6)] = q; }
    __syncthreads();
    double S = sc[0] + sc[1] + sc[2] + sc[3];
    double Q = sc[4] + sc[5] + sc[6] + sc[7];
    double mu = S * (1.0 / 768.0);
    double rs = rsqrt(Q * (1.0 / 768.0) - mu * mu + 1e-5);
    for (int j = tid; j < 768; j += 256)
        buf[j] = (buf[j] - mu) * rs * (double)qp_g[j] + (double)qp_b[j];
    __syncthreads();
    {
        double acc0 = 0., acc1 = 0., acc2 = 0.;
        for (int k0 = 0; k0 < 768; k0 += 8) {
            __syncthreads();   // prior-slab reads done before overwrite
            const float4* src = (const float4*)(qp_W + (size_t)k0 * 768);
#pragma unroll
            for (int t = 0; t < 6; t++)
                ((float4*)Ws)[tid + (t << 8)] = src[tid + (t << 8)];
            __syncthreads();
#pragma unroll
            for (int u = 0; u < 8; u++) {
                double a = buf[k0 + u];
                acc0 = fma(a, (double)Ws[u][tid], acc0);
                acc1 = fma(a, (double)Ws[u][tid + 256], acc1);
                acc2 = fma(a, (double)Ws[u][tid + 512], acc2);
            }
        }
        qa2d[(size_t)i * 768 + tid] = gelud(acc0 + (double)qp_bias[tid]);
        qa2d[(size_t)i * 768 + tid + 256] = gelud(acc1 + (double)qp_bias[tid + 256]);
        qa2d[(size_t)i * 768 + tid + 512] = gelud(acc2 + (double)qp_bias[tid + 512]);
    }
}

// ---------------------------------------------------------------------------
// Stage 2: v2 rows. 4 rows per block (8 blocks/batch), KT=8 LDS-staged W.
// ---------------------------------------------------------------------------
__global__ __launch_bounds__(256) void repair_v2_k(
    const float* __restrict__ v, const float* __restrict__ vp_g,
    const float* __restrict__ vp_b, const float* __restrict__ vp_W,
    const float* __restrict__ vp_bias, const int* __restrict__ cnt,
    const int* __restrict__ list, double* __restrict__ v2d) {
    int n = *cnt; if (n > CAP) n = CAP;
    int i = blockIdx.x >> 3, rg = blockIdx.x & 7;
    if (i >= n) return;
    int b = list[i];
    __shared__ double A[4][768];
    __shared__ float Ws[8][768];
    __shared__ double sc[8];
    int tid = threadIdx.x;
    for (int r = 0; r < 4; r++) {
        const float* vr = v + ((size_t)(b * 32 + rg * 4 + r)) * 768;
        double s = 0., q = 0.;
        for (int j = tid; j < 768; j += 256) {
            double x = (double)vr[j];
            A[r][j] = x; s += x; q += x * x;
        }
#pragma unroll
        for (int m = 1; m < 64; m <<= 1) {
            s += __shfl_xor(s, m, 64);
            q += __shfl_xor(q, m, 64);
        }
        if ((tid & 63) == 0) { sc[tid >> 6] = s; sc[4 + (tid >> 6)] = q; }
        __syncthreads();
        double S = sc[0] + sc[1] + sc[2] + sc[3];
        double Q = sc[4] + sc[5] + sc[6] + sc[7];
        double mu = S * (1.0 / 768.0);
        double rs = rsqrt(Q * (1.0 / 768.0) - mu * mu + 1e-5);
        for (int j = tid; j < 768; j += 256)
            A[r][j] = (A[r][j] - mu) * rs * (double)vp_g[j] + (double)vp_b[j];
        __syncthreads();
    }
    {
        double acc[3][4] = {};
        for (int k0 = 0; k0 < 768; k0 += 8) {
            __syncthreads();
            const float4* src = (const float4*)(vp_W + (size_t)k0 * 768);
#pragma unroll
            for (int t = 0; t < 6; t++)
                ((float4*)Ws)[tid + (t << 8)] = src[tid + (t << 8)];
            __syncthreads();
#pragma unroll
            for (int u = 0; u < 8; u++) {
                double w0 = (double)Ws[u][tid];
                double w1 = (double)Ws[u][tid + 256];
                double w2_ = (double)Ws[u][tid + 512];
#pragma unroll
                for (int r = 0; r < 4; r++) {
                    double a = A[r][k0 + u];
                    acc[0][r] = fma(a, w0, acc[0][r]);
                    acc[1][r] = fma(a, w1, acc[1][r]);
                    acc[2][r] = fma(a, w2_, acc[2][r]);
                }
            }
        }
        size_t base = (size_t)i * 32 + rg * 4;
#pragma unroll
        for (int jj = 0; jj < 3; jj++) {
            int j = tid + (jj << 8);
            double bias = (double)vp_bias[j];
#pragma unroll
            for (int r = 0; r < 4; r++)
                v2d[(base + r) * 768 + j] = gelud(acc[jj][r] + bias);
        }
    }
}

// ---------------------------------------------------------------------------
// Stage 3: gate + folded LN + h GEMM + logit. 4 rows per block
// (8 blocks/batch), KT=8 LDS-staged W1 (rows padded to 512 floats).
// ---------------------------------------------------------------------------
__global__ __launch_bounds__(256) void repair_h_k(
    const double* __restrict__ v2d, const double* __restrict__ qa2d,
    const float* __restrict__ gr_g, const float* __restrict__ gr_b,
    const float* __restrict__ gr_W1, const float* __restrict__ gr_b1,
    const float* __restrict__ gr_W2, const float* __restrict__ gr_b2,
    const int* __restrict__ cnt, const int* __restrict__ list,
    double* __restrict__ lgd_out) {
    int n = *cnt; if (n > CAP) n = CAP;
    int i = blockIdx.x >> 3, rg = blockIdx.x & 7;
    if (i >= n) return;
    __shared__ double A[4][768];
    __shared__ float Ws[8][512];   // 384 used, padded for safe idx
    __shared__ double sc[12];
    __shared__ double red[4][4];
    int tid = threadIdx.x;
    const double* qrow = qa2d + (size_t)i * 768;
    for (int r = 0; r < 4; r++) {
        const double* vr = v2d + ((size_t)i * 32 + rg * 4 + r) * 768;
        double s = 0., q = 0., dot = 0.;
        for (int j = tid; j < 768; j += 256) {
            double x = vr[j];
            A[r][j] = x; s += x; q += x * x; dot += x * qrow[j];
        }
#pragma unroll
        for (int m = 1; m < 64; m <<= 1) {
            s += __shfl_xor(s, m, 64);
            q += __shfl_xor(q, m, 64);
            dot += __shfl_xor(dot, m, 64);
        }
        if ((tid & 63) == 0) {
            int w = tid >> 6;
            sc[w] = s; sc[4 + w] = q; sc[8 + w] = dot;
        }
        __syncthreads();
        double S = sc[0] + sc[1] + sc[2] + sc[3];
        double Q = sc[4] + sc[5] + sc[6] + sc[7];
        double Dt = sc[8] + sc[9] + sc[10] + sc[11];
        double gate = tanh(Dt);
        double mu = gate * (S * (1.0 / 768.0));
        double var = gate * gate * (Q * (1.0 / 768.0)) - mu * mu;
        double rs = rsqrt(var + 1e-5);
        double s1v = gate * rs, s2v = mu * rs;
        for (int j = tid; j < 768; j += 256)
            A[r][j] = (double)gr_g[j] * (A[r][j] * s1v - s2v) + (double)gr_b[j];
        __syncthreads();
    }
    double part[4] = {};
    {
        const bool hi = (tid < 128);   // wave-uniform (waves 0,1 true; 2,3 false)
        double acc[2][4] = {};
        for (int k0 = 0; k0 < 768; k0 += 8) {
            __syncthreads();
            const float* src = gr_W1 + (size_t)k0 * 384;
            // 8x384 floats = 768 float4; thread loads 3 (row = f/96)
#pragma unroll
            for (int t = 0; t < 3; t++) {
                int f = tid + (t << 8);
                int kr = f / 96;
                int fc = (f - kr * 96) << 2;
                *(float4*)&Ws[kr][fc] = *(const float4*)&src[(size_t)kr * 384 + fc];
            }
            __syncthreads();
#pragma unroll
            for (int u = 0; u < 8; u++) {
                double w0 = (double)Ws[u][tid];
                double w1 = hi ? (double)Ws[u][tid + 256] : 0.;
#pragma unroll
                for (int r = 0; r < 4; r++) {
                    double a = A[r][k0 + u];
                    acc[0][r] = fma(a, w0, acc[0][r]);
                    acc[1][r] = fma(a, w1, acc[1][r]);
                }
            }
        }
        {
            double b1 = (double)gr_b1[tid], w2 = (double)gr_W2[tid];
#pragma unroll
            for (int r = 0; r < 4; r++) part[r] += gelud(acc[0][r] + b1) * w2;
        }
        if (hi) {
            double b1 = (double)gr_b1[tid + 256], w2 = (double)gr_W2[tid + 256];
#pragma unroll
            for (int r = 0; r < 4; r++) part[r] += gelud(acc[1][r] + b1) * w2;
        }
    }
#pragma unroll
    for (int r = 0; r < 4; r++)
#pragma unroll
        for (int m = 1; m < 64; m <<= 1) part[r] += __shfl_xor(part[r], m, 64);
    if ((tid & 63) == 0) {
        int w = tid >> 6;
#pragma unroll
        for (int r = 0; r < 4; r++) red[w][r] = part[r];
    }
    __syncthreads();
    if (tid < 4) {
        double t = red[0][tid] + red[1][tid] + red[2][tid] + red[3][tid] +
                   (double)gr_b2[0];
        lgd_out[(size_t)i * 32 + rg * 4 + tid] = t;
    }
}

// ---------------------------------------------------------------------------
// Stage 4: fp64 tail + output overwrite per flagged batch.
// ---------------------------------------------------------------------------
__global__ __launch_bounds__(64) void repair_fin_k(
    const double* __restrict__ lgd_in, const float* __restrict__ sigma,
    const int* __restrict__ cnt, const int* __restrict__ list,
    float* __restrict__ out) {
    int n = *cnt; if (n > CAP) n = CAP;
    int i = blockIdx.x;
    if (i >= n) return;
    int b = list[i];
    int l = threadIdx.x;
    __shared__ double lgd[32], gsd[32];
    __shared__ int sb[2];
    if (l < 32) lgd[l] = lgd_in[(size_t)i * 32 + l];
    __syncthreads();
    if (l == 0) {
        int st, en, flag;
        tail_fp64(lgd, (double)sigma[0], gsd, &st, &en, &flag, 0.);
        sb[0] = st;
        sb[1] = en;
    }
    __syncthreads();
    write_outputs(out, b, gsd, lgd, sb[0], sb[1], l);
}

// ---------------------------------------------------------------------------
// Fallback: monolithic fp64 repair for flagged batches beyond CAP (rare).
// ---------------------------------------------------------------------------
__global__ __launch_bounds__(256) void repair_slow_k(
    const float* __restrict__ v, const float* __restrict__ qa,
    const float* __restrict__ vp_g, const float* __restrict__ vp_b,
    const float* __restrict__ vp_W, const float* __restrict__ vp_bias,
    const float* __restrict__ qp_g, const float* __restrict__ qp_b,
    const float* __restrict__ qp_W, const float* __restrict__ qp_bias,
    const float* __restrict__ gr_g, const float* __restrict__ gr_b,
    const float* __restrict__ gr_W1, const float* __restrict__ gr_b1,
    const float* __restrict__ gr_W2, const float* __restrict__ gr_b2,
    const float* __restrict__ sigma, const int* __restrict__ cnt,
    const int* __restrict__ list, float* __restrict__ out) {
    __shared__ double qa2d[768];
    __shared__ double buf[768];
    __shared__ double v2r[768];
    __shared__ double hln[768];
    __shared__ double lgd[32], gsd[32];
    __shared__ double sc[12];
    __shared__ int sb[2];
    const int tid = threadIdx.x;
    const int n = *cnt;

    for (int ii = CAP + blockIdx.x; ii < n; ii += gridDim.x) {
        const int b = list[ii];
        double s = 0., q = 0.;
        for (int j = tid; j < 768; j += 256) {
            double x = (double)qa[(size_t)b * 768 + j];
            buf[j] = x; s += x; q += x * x;
        }
#pragma unroll
        for (int m = 1; m < 64; m <<= 1) {
            s += __shfl_xor(s, m, 64);
            q += __shfl_xor(q, m, 64);
        }
        if ((tid & 63) == 0) { sc[tid >> 6] = s; sc[4 + (tid >> 6)] = q; }
        __syncthreads();
        {
            double S = sc[0] + sc[1] + sc[2] + sc[3];
            double Q = sc[4] + sc[5] + sc[6] + sc[7];
            double mu = S * (1.0 / 768.0);
            double rs = rsqrt(Q * (1.0 / 768.0) - mu * mu + 1e-5);
            for (int j = tid; j < 768; j += 256)
                buf[j] = (buf[j] - mu) * rs * (double)qp_g[j] + (double)qp_b[j];
        }
        __syncthreads();
        for (int j = tid; j < 768; j += 256) {
            double acc = 0.;
#pragma unroll 8
            for (int k = 0; k < 768; k++)
                acc = fma(buf[k], (double)qp_W[(size_t)k * 768 + j], acc);
            qa2d[j] = gelud(acc + (double)qp_bias[j]);
        }
        __syncthreads();

        for (int r = 0; r < 32; r++) {
            const float* vr = v + ((size_t)(b * 32 + r)) * 768;
            s = 0.; q = 0.;
            for (int j = tid; j < 768; j += 256) {
                double x = (double)vr[j];
                buf[j] = x; s += x; q += x * x;
            }
#pragma unroll
            for (int m = 1; m < 64; m <<= 1) {
                s += __shfl_xor(s, m, 64);
                q += __shfl_xor(q, m, 64);
            }
            if ((tid & 63) == 0) { sc[tid >> 6] = s; sc[4 + (tid >> 6)] = q; }
            __syncthreads();
            {
                double S = sc[0] + sc[1] + sc[2] + sc[3];
                double Q = sc[4] + sc[5] + sc[6] + sc[7];
                double mu = S * (1.0 / 768.0);
                double rs = rsqrt(Q * (1.0 / 768.0) - mu * mu + 1e-5);
                for (int j = tid; j < 768; j += 256)
                    buf[j] = (buf[j] - mu) * rs * (double)vp_g[j] + (double)vp_b[j];
            }
            __syncthreads();
            for (int j = tid; j < 768; j += 256) {
                double acc = 0.;
#pragma unroll 8
                for (int k = 0; k < 768; k++)
                    acc = fma(buf[k], (double)vp_W[(size_t)k * 768 + j], acc);
                v2r[j] = gelud(acc + (double)vp_bias[j]);
            }
            __syncthreads();
            double dot = 0.;
            s = 0.; q = 0.;
            for (int j = tid; j < 768; j += 256) {
                double x = v2r[j];
                dot += x * qa2d[j]; s += x; q += x * x;
            }
#pragma unroll
            for (int m = 1; m < 64; m <<= 1) {
                dot += __shfl_xor(dot, m, 64);
                s += __shfl_xor(s, m, 64);
                q += __shfl_xor(q, m, 64);
            }
            if ((tid & 63) == 0) {
                sc[tid >> 6] = s;
                sc[4 + (tid >> 6)] = q;
                sc[8 + (tid >> 6)] = dot;
            }
            __syncthreads();
            {
                double S = sc[0] + sc[1] + sc[2] + sc[3];
                double Q = sc[4] + sc[5] + sc[6] + sc[7];
                double Dt = sc[8] + sc[9] + sc[10] + sc[11];
                double gate = tanh(Dt);
                double mu = gate * (S * (1.0 / 768.0));
                double var = gate * gate * (Q * (1.0 / 768.0)) - mu * mu;
                double rs = rsqrt(var + 1e-5);
                double s1v = gate * rs, s2v = mu * rs;
                for (int j = tid; j < 768; j += 256)
                    hln[j] = (double)gr_g[j] * (v2r[j] * s1v - s2v) + (double)gr_b[j];
            }
            __syncthreads();
            double part = 0.;
            for (int j = tid; j < 384; j += 256) {
                double acc = 0.;
#pragma unroll 8
                for (int k = 0; k < 768; k++)
                    acc = fma(hln[k], (double)gr_W1[(size_t)k * 384 + j], acc);
                part += gelud(acc + (double)gr_b1[j]) * (double)gr_W2[j];
            }
#pragma unroll
            for (int m = 1; m < 64; m <<= 1) part += __shfl_xor(part, m, 64);
            if ((tid & 63) == 0) sc[tid >> 6] = part;
            __syncthreads();
            if (tid == 0) lgd[r] = sc[0] + sc[1] + sc[2] + sc[3] + (double)gr_b2[0];
            __syncthreads();
        }
        if (tid == 0) {
            int st, en, flag;
            tail_fp64(lgd, (double)sigma[0], gsd, &st, &en, &flag, 0.);
            sb[0] = st;
            sb[1] = en;
        }
        __syncthreads();
        write_outputs(out, b, gsd, lgd, sb[0], sb[1], tid);
        __syncthreads();
    }
}

// ---------------------------------------------------------------------------
extern "C" void kernel_launch(void* const* d_in, const int* in_sizes, int n_in,
                              void* d_out, int out_size, void* d_ws, size_t ws_size,
                              hipStream_t stream) {
    (void)in_sizes; (void)n_in; (void)out_size;
    const float* v = (const float*)d_in[0];
    const float* qa = (const float*)d_in[1];
    const float* vp_g = (const float*)d_in[2];
    const float* vp_b = (const float*)d_in[3];
    const float* vp_W = (const float*)d_in[4];
    const float* vp_bias = (const float*)d_in[5];
    const float* qp_g = (const float*)d_in[6];
    const float* qp_b = (const float*)d_in[7];
    const float* qp_W = (const float*)d_in[8];
    const float* qp_bias = (const float*)d_in[9];
    const float* gr_g = (const float*)d_in[10];
    const float* gr_b = (const float*)d_in[11];
    const float* gr_W1 = (const float*)d_in[12];
    const float* gr_b1 = (const float*)d_in[13];
    const float* gr_W2 = (const float*)d_in[14];
    const float* gr_b2 = (const float*)d_in[15];
    const float* sigma = (const float*)d_in[16];
    float* out = (float*)d_out;

    // ws: [cnt(8 ints) | list(4096 ints) | pad to 32KB] [fp64 repair buffers]
    //     [fp16 split-transposed weights] [fp32 main-path scratch]
    int* cnt = (int*)d_ws;
    int* list = cnt + 8;
    hipMemsetAsync(d_ws, 0, 32, stream);
    double* qa2d = (double*)((char*)d_ws + 32768);
    double* v2d = qa2d + (size_t)CAP * 768;
    double* lgdr = v2d + (size_t)CAP * 32 * 768;
    unsigned short* qWhi = (unsigned short*)(lgdr + (size_t)CAP * 32);
    unsigned short* qWlo = qWhi + (size_t)DD * DD;
    unsigned short* vWhi = qWlo + (size_t)DD * DD;
    unsigned short* vWlo = vWhi + (size_t)DD * DD;
    unsigned short* w1hi = vWlo + (size_t)DD * DD;
    unsigned short* w1lo = w1hi + (size_t)DD * HH;
    float* p = (float*)(w1lo + (size_t)DD * HH);

    size_t head_floats = (size_t)((char*)p - (char*)d_ws) / 4;
    float* qa_mean = p; p += BSZ;
    float* qa_rstd = p; p += BSZ;
    float* qa2 = p; p += (size_t)BSZ * DD;
    float* logits = p; p += (size_t)BSZ * LL;

    size_t fixed = head_floats + (size_t)BSZ * 2 + (size_t)BSZ * DD + (size_t)BSZ * LL;
    int bpc = 1024;
    while (bpc > 32) {
        size_t rows = (size_t)bpc * LL;
        size_t need = fixed + rows * 4 + rows * DD;
        if (need * sizeof(float) <= ws_size) break;
        bpc >>= 1;
    }
    size_t rows = (size_t)bpc * LL;
    float* v_mean = p; p += rows;
    float* v_rstd = p; p += rows;
    float* s1 = p; p += rows;
    float* s2 = p; p += rows;
    float* v2 = p; p += rows * DD;

    // one-time: split+transpose weights to fp16 hi/lo
    wsplit_k<<<dim3(12, 12), dim3(256), 0, stream>>>(qp_W, qWhi, qWlo, DD);
    wsplit_k<<<dim3(12, 12), dim3(256), 0, stream>>>(vp_W, vWhi, vWlo, DD);
    wsplit_k<<<dim3(6, 12), dim3(256), 0, stream>>>(gr_W1, w1hi, w1lo, HH);

    // qa path (once)
    row_stats_k<<<dim3((unsigned)((BSZ * 64) / 256)), dim3(256), 0, stream>>>(
        qa, qa_mean, qa_rstd, BSZ);
    gemm_ln_gelu_k<<<dim3(BSZ / 128, DD / 128), dim3(256), 0, stream>>>(
        qa, qa_mean, qa_rstd, qp_g, qp_b, qWhi, qWlo, qp_bias, qa2);

    int nch = BSZ / bpc;
    for (int c = 0; c < nch; c++) {
        int rowbase = c * (int)rows;
        const float* vchunk = v + (size_t)rowbase * DD;
        row_stats_k<<<dim3((unsigned)((rows * 64) / 256)), dim3(256), 0, stream>>>(
            vchunk, v_mean, v_rstd, (int)rows);
        gemm_ln_gelu_k<<<dim3((unsigned)(rows / 128), DD / 128), dim3(256), 0, stream>>>(
            vchunk, v_mean, v_rstd, vp_g, vp_b, vWhi, vWlo, vp_bias, v2);
        gate_stats_k<<<dim3((unsigned)((rows * 64) / 256)), dim3(256), 0, stream>>>(
            v2, qa2, s1, s2, logits, gr_b2, rowbase, (int)rows);
        gemm_h_logits_k<<<dim3((unsigned)(rows / 128), HH / 128), dim3(256), 0, stream>>>(
            v2, s1, s2, gr_g, gr_b, w1hi, w1lo, gr_b1, gr_W2, logits + rowbase);
    }
    finalize_detect_k<<<dim3(BSZ), dim3(64), 0, stream>>>(logits, sigma, out, cnt, list);
    // gathered fp64 repair for flagged batches (<= CAP)
    repair_qa_k<<<dim3(CAP), dim3(256), 0, stream>>>(
        qa, qp_g, qp_b, qp_W, qp_bias, cnt, list, qa2d);
    repair_v2_k<<<dim3(CAP * 8), dim3(256), 0, stream>>>(
        v, vp_g, vp_b, vp_W, vp_bias, cnt, list, v2d);
    repair_h_k<<<dim3(CAP * 8), dim3(256), 0, stream>>>(
        v2d, qa2d, gr_g, gr_b, gr_W1, gr_b1, gr_W2, gr_b2, cnt, list, lgdr);
    repair_fin_k<<<dim3(CAP), dim3(64), 0, stream>>>(lgdr, sigma, cnt, list, out);
    // overflow fallback (no-op unless > CAP batches flagged)
    repair_slow_k<<<dim3(256), dim3(256), 0, stream>>>(
        v, qa, vp_g, vp_b, vp_W, vp_bias, qp_g, qp_b, qp_W, qp_bias,
        gr_g, gr_b, gr_W1, gr_b1, gr_W2, gr_b2, sigma, cnt, list, out);
}